// Round 6
// baseline (191.563 us; speedup 1.0000x reference)
//
#include <hip/hip_runtime.h>
#include <hip/hip_bf16.h>

#define S_LEN 4096
#define HID   512
#define HD    128
#define LOG2_GAMMA (-0.0458036933f)   // log2(0.96875)

typedef short bf16x8 __attribute__((ext_vector_type(8)));
typedef float f32x4  __attribute__((ext_vector_type(4)));
typedef unsigned short u16;

static __device__ __forceinline__ u16 f2bf(float f) {
    union { float f; unsigned u; } v; v.f = f;
    unsigned r = (v.u + 0x7fffu + ((v.u >> 16) & 1u)) >> 16;  // RNE
    return (u16)r;
}

static __device__ __forceinline__ unsigned pk2(float lo, float hi) {
    __hip_bfloat162 h = __float22bfloat162_rn(make_float2(lo, hi));
    union { __hip_bfloat162 h; unsigned u; } c; c.h = h; return c.u;
}
static __device__ __forceinline__ bf16x8 pack8(float4 a, float4 b) {
    union { unsigned u[4]; bf16x8 v; } r;
    r.u[0] = pk2(a.x, a.y); r.u[1] = pk2(a.z, a.w);
    r.u[2] = pk2(b.x, b.y); r.u[3] = pk2(b.z, b.w);
    return r.v;
}

// ---------------- xpos tables: tab[n*64+i] = (cos*scale, sin*scale) ----------------
__global__ __launch_bounds__(256) void xpos_table_kernel(float2* __restrict__ tabQ,
                                                         float2* __restrict__ tabK) {
    int idx = blockIdx.x * 256 + threadIdx.x;      // 4096*64 items
    int n = idx >> 6, i = idx & 63;
    float base  = (2.0f * i + 51.2f) * (1.0f / 179.2f);       // (2i+0.4d)/(1.4d), d=128
    float power = (float)n * (1.0f / 512.0f);
    float scale = exp2f(power * log2f(base));
    float inv_freq = exp2f(-(float)i * (13.287712379549449f / 64.0f)); // 10000^(-i/64)
    float theta = (float)n * inv_freq;
    float s, c;
    sincosf(theta, &s, &c);
    tabQ[idx] = make_float2(c * scale, s * scale);
    float is = 1.0f / scale;
    tabK[idx] = make_float2(c * is, s * is);
}

// ---------------- weight transpose -> bf16, Wt[w][col][k] ----------------
__global__ __launch_bounds__(256) void wt_kernel(const float* __restrict__ WQ,
                                                 const float* __restrict__ WK,
                                                 const float* __restrict__ WV,
                                                 u16* __restrict__ Wt) {
    int idx = blockIdx.x * 256 + threadIdx.x;      // 3*128*512
    int w = idx >> 16;
    int rem = idx & 65535;
    int c = rem >> 9, k = rem & 511;
    const float* src = (w == 0) ? WQ : (w == 1) ? WK : WV;
    Wt[idx] = f2bf(src[k * HD + c]);
}

// ---------------- proj v6: barrier-free K-loop, direct reg loads, fused Q|KV -------
// grid (256, 2); block 256 (4 waves). Tile 64 tokens x 128 cols, 16 chunks of BK=32.
// No LDS in the K-loop: A frag = lane's own 32B (16x128B full cachelines per instr),
// B frags direct from L2-hot weights. Register double-buffer, fine-vmcnt pipelining.
__global__ __launch_bounds__(256) void proj_kernel(const float* __restrict__ X,
                                                   const float* __restrict__ Mem,
                                                   const u16* __restrict__ Wt,
                                                   const float2* __restrict__ tabQ,
                                                   const float2* __restrict__ tabK,
                                                   u16* __restrict__ Qo,
                                                   u16* __restrict__ Ko,
                                                   u16* __restrict__ Vt) {
    __shared__ u16 Vs[128 * 80];     // 20KB transpose scratch (y=1 only)
    const int tid  = threadIdx.x;
    const int wave = tid >> 6, lane = tid & 63;
    const int l15  = lane & 15, quad = lane >> 4;
    const int rt_base = blockIdx.x * 64;

    if (blockIdx.y == 0) {
        // ------------------------------ Q from X ------------------------------
        const float* arow = X + (size_t)(rt_base + wave * 16 + l15) * HID + quad * 8;
        const u16*   bb   = Wt + (size_t)l15 * HID + quad * 8;

        f32x4 acc[8];
#pragma unroll
        for (int ct = 0; ct < 8; ++ct) acc[ct] = (f32x4){0.f, 0.f, 0.f, 0.f};

        float4 a0 = *(const float4*)arow;
        float4 a1 = *(const float4*)(arow + 4);
        bf16x8 bc[8];
#pragma unroll
        for (int ct = 0; ct < 8; ++ct) bc[ct] = *(const bf16x8*)(bb + ct * 16 * HID);

        for (int ch = 0; ch < 16; ++ch) {
            float4 an0, an1; bf16x8 bn[8];
            if (ch < 15) {
                an0 = *(const float4*)(arow + (ch + 1) * 32);
                an1 = *(const float4*)(arow + (ch + 1) * 32 + 4);
#pragma unroll
                for (int ct = 0; ct < 8; ++ct)
                    bn[ct] = *(const bf16x8*)(bb + ct * 16 * HID + (ch + 1) * 32);
            }
            bf16x8 a = pack8(a0, a1);
#pragma unroll
            for (int ct = 0; ct < 8; ++ct)
                acc[ct] = __builtin_amdgcn_mfma_f32_16x16x32_bf16(a, bc[ct], acc[ct], 0, 0, 0);
            if (ch < 15) {
                a0 = an0; a1 = an1;
#pragma unroll
                for (int ct = 0; ct < 8; ++ct) bc[ct] = bn[ct];
            }
        }

        // xpos epilogue (table)
#pragma unroll
        for (int ct = 0; ct < 8; ++ct) {
            int j = ct * 16 + l15;
            int i = j >> 1;
            float sgn = (j & 1) ? 1.0f : -1.0f;
#pragma unroll
            for (int r = 0; r < 4; ++r) {
                int t = rt_base + wave * 16 + quad * 4 + r;
                int n = t & 4095;
                float2 cs = tabQ[n * 64 + i];
                float v = acc[ct][r];
                float partner = __shfl_xor(v, 1, 64);
                Qo[(size_t)t * HD + j] = f2bf(v * cs.x + sgn * partner * cs.y);
            }
        }
    } else {
        // --------------------------- K and V from Mem -------------------------
        const float* arow = Mem + (size_t)(rt_base + wave * 16 + l15) * HID + quad * 8;
        const u16*   bbK  = Wt + 65536  + (size_t)l15 * HID + quad * 8;
        const u16*   bbV  = Wt + 131072 + (size_t)l15 * HID + quad * 8;

        f32x4 acc0[8], acc1[8];
#pragma unroll
        for (int ct = 0; ct < 8; ++ct) {
            acc0[ct] = (f32x4){0.f, 0.f, 0.f, 0.f};
            acc1[ct] = (f32x4){0.f, 0.f, 0.f, 0.f};
        }

        float4 a0 = *(const float4*)arow;
        float4 a1 = *(const float4*)(arow + 4);
        bf16x8 bcK[8], bcV[8];
#pragma unroll
        for (int ct = 0; ct < 8; ++ct) {
            bcK[ct] = *(const bf16x8*)(bbK + ct * 16 * HID);
            bcV[ct] = *(const bf16x8*)(bbV + ct * 16 * HID);
        }

        for (int ch = 0; ch < 16; ++ch) {
            float4 an0, an1; bf16x8 bnK[8], bnV[8];
            if (ch < 15) {
                an0 = *(const float4*)(arow + (ch + 1) * 32);
                an1 = *(const float4*)(arow + (ch + 1) * 32 + 4);
#pragma unroll
                for (int ct = 0; ct < 8; ++ct) {
                    bnK[ct] = *(const bf16x8*)(bbK + ct * 16 * HID + (ch + 1) * 32);
                    bnV[ct] = *(const bf16x8*)(bbV + ct * 16 * HID + (ch + 1) * 32);
                }
            }
            bf16x8 a = pack8(a0, a1);
#pragma unroll
            for (int ct = 0; ct < 8; ++ct) {
                acc0[ct] = __builtin_amdgcn_mfma_f32_16x16x32_bf16(a, bcK[ct], acc0[ct], 0, 0, 0);
                acc1[ct] = __builtin_amdgcn_mfma_f32_16x16x32_bf16(a, bcV[ct], acc1[ct], 0, 0, 0);
            }
            if (ch < 15) {
                a0 = an0; a1 = an1;
#pragma unroll
                for (int ct = 0; ct < 8; ++ct) { bcK[ct] = bnK[ct]; bcV[ct] = bnV[ct]; }
            }
        }

        // K xpos epilogue (table)
#pragma unroll
        for (int ct = 0; ct < 8; ++ct) {
            int j = ct * 16 + l15;
            int i = j >> 1;
            float sgn = (j & 1) ? 1.0f : -1.0f;
#pragma unroll
            for (int r = 0; r < 4; ++r) {
                int t = rt_base + wave * 16 + quad * 4 + r;
                int n = t & 4095;
                float2 cs = tabK[n * 64 + i];
                float v = acc0[ct][r];
                float partner = __shfl_xor(v, 1, 64);
                Ko[(size_t)t * HD + j] = f2bf(v * cs.x + sgn * partner * cs.y);
            }
        }

        // V transpose via dedicated LDS scratch -> Vt[b][h][s] bf16
#pragma unroll
        for (int ct = 0; ct < 8; ++ct) {
            int col = ct * 16 + l15;
#pragma unroll
            for (int r = 0; r < 4; ++r)
                Vs[col * 80 + wave * 16 + quad * 4 + r] = f2bf(acc1[ct][r]);
        }
        __syncthreads();
        int b = rt_base >> 12, sb = rt_base & 4095;
        int h = tid >> 1, sof = (tid & 1) * 32;
#pragma unroll
        for (int pp = 0; pp < 4; ++pp) {
            bf16x8 v = *(const bf16x8*)&Vs[h * 80 + sof + pp * 8];
            *(bf16x8*)(Vt + (size_t)(b * 128 + h) * S_LEN + sb + sof + pp * 8) = v;
        }
    }
}

// ---------------- windowed retention v4: fully barrier-free ------------------------
// grid 256 (b*64 + qtile64); block 256 (4 waves, wave owns 16 q-rows).
// K and V fragments loaded directly global->VGPR (Kb/Vt are L2-hot, 8MB total);
// P strip is wave-private LDS (lgkmcnt-only). Zero __syncthreads in the KV loop.
__global__ __launch_bounds__(256) void ret_kernel(const u16* __restrict__ Qb,
                                                  const u16* __restrict__ Kb,
                                                  const u16* __restrict__ Vt,
                                                  float* __restrict__ out) {
    __shared__ __align__(16) float P_lds[4][16][68];    // per-wave 16x64 fp32 strip
    const int tid  = threadIdx.x;
    const int wave = tid >> 6, lane = tid & 63;
    const int l15  = lane & 15, quad = lane >> 4;
    const int b  = blockIdx.x >> 6;
    const int qt = (blockIdx.x & 63) * 64;
    const int qw = qt + wave * 16;

    const size_t tq = (size_t)(b * S_LEN + qw + l15);
    bf16x8 qfrag[4];
#pragma unroll
    for (int kc = 0; kc < 4; ++kc)
        qfrag[kc] = *(const bf16x8*)(Qb + tq * HD + kc * 32 + quad * 8);

    f32x4 acco[8];
#pragma unroll
    for (int ht = 0; ht < 8; ++ht) acco[ht] = (f32x4){0.f, 0.f, 0.f, 0.f};

    int kv_lo = qt - 448; if (kv_lo < 0) kv_lo = 0;   // γ^449 ≈ 6e-7: below threshold
    const int nt = (qt + 64 - kv_lo) >> 6;

    for (int it = 0; it < nt; ++it) {
        const int kv0 = kv_lo + it * 64;

        // K fragments direct (B-operand rows = kv positions)
        bf16x8 kf[4][4];
#pragma unroll
        for (int ct = 0; ct < 4; ++ct) {
            const u16* kb = Kb + (size_t)(b * S_LEN + kv0 + ct * 16 + l15) * HD + quad * 8;
#pragma unroll
            for (int kc = 0; kc < 4; ++kc)
                kf[ct][kc] = *(const bf16x8*)(kb + kc * 32);
        }
        // V fragments direct
        bf16x8 vf[8][2];
#pragma unroll
        for (int ht = 0; ht < 8; ++ht) {
            const u16* vb = Vt + (size_t)(b * HD + ht * 16 + l15) * S_LEN + kv0 + quad * 8;
            vf[ht][0] = *(const bf16x8*)vb;
            vf[ht][1] = *(const bf16x8*)(vb + 32);
        }

        // ---- S = Q K^T (16x64 per wave) ----
        f32x4 accs[4];
#pragma unroll
        for (int ct = 0; ct < 4; ++ct) accs[ct] = (f32x4){0.f, 0.f, 0.f, 0.f};
#pragma unroll
        for (int ct = 0; ct < 4; ++ct)
#pragma unroll
            for (int kc = 0; kc < 4; ++kc)
                accs[ct] = __builtin_amdgcn_mfma_f32_16x16x32_bf16(qfrag[kc], kf[ct][kc], accs[ct], 0, 0, 0);

        // ---- decay + causal mask -> wave-private P strip (no barrier) ----
#pragma unroll
        for (int ct = 0; ct < 4; ++ct) {
            int kvi = kv0 + ct * 16 + l15;
#pragma unroll
            for (int r = 0; r < 4; ++r) {
                int d = (qw + quad * 4 + r) - kvi;
                float w = exp2f((float)d * LOG2_GAMMA);
                P_lds[wave][quad * 4 + r][ct * 16 + l15] = (d >= 0) ? accs[ct][r] * w : 0.0f;
            }
        }
        // ---- P as A-fragments (within-wave lgkmcnt only) ----
        float4 p00 = *(const float4*)&P_lds[wave][l15][quad * 8];
        float4 p01 = *(const float4*)&P_lds[wave][l15][quad * 8 + 4];
        float4 p10 = *(const float4*)&P_lds[wave][l15][32 + quad * 8];
        float4 p11 = *(const float4*)&P_lds[wave][l15][32 + quad * 8 + 4];
        bf16x8 pa0 = pack8(p00, p01);
        bf16x8 pa1 = pack8(p10, p11);
        // ---- O += P V ----
#pragma unroll
        for (int ht = 0; ht < 8; ++ht) {
            acco[ht] = __builtin_amdgcn_mfma_f32_16x16x32_bf16(pa0, vf[ht][0], acco[ht], 0, 0, 0);
            acco[ht] = __builtin_amdgcn_mfma_f32_16x16x32_bf16(pa1, vf[ht][1], acco[ht], 0, 0, 0);
        }
    }

#pragma unroll
    for (int ht = 0; ht < 8; ++ht)
#pragma unroll
        for (int r = 0; r < 4; ++r)
            out[(size_t)(b * S_LEN + qw + quad * 4 + r) * HD + ht * 16 + l15] = acco[ht][r];
}

extern "C" void kernel_launch(void* const* d_in, const int* in_sizes, int n_in,
                              void* d_out, int out_size, void* d_ws, size_t ws_size,
                              hipStream_t stream) {
    const float* X   = (const float*)d_in[0];
    const float* Mem = (const float*)d_in[1];
    const float* WQ  = (const float*)d_in[2];
    const float* WK  = (const float*)d_in[3];
    const float* WV  = (const float*)d_in[4];
    float* out = (float*)d_out;

    char* ws = (char*)d_ws;
    u16*    Qb   = (u16*)(ws);                         // 4 MB  bf16 [16384][128]
    u16*    Kb   = (u16*)(ws + ((size_t)4 << 20));     // 4 MB
    u16*    Vt   = (u16*)(ws + ((size_t)8 << 20));     // 4 MB  bf16 [4][128][4096]
    u16*    Wt   = (u16*)(ws + ((size_t)12 << 20));    // 384 KB bf16 [3][128][512]
    float2* tabQ = (float2*)(ws + ((size_t)13 << 20)); // 2 MB
    float2* tabK = (float2*)(ws + ((size_t)15 << 20)); // 2 MB

    xpos_table_kernel<<<dim3(1024), dim3(256), 0, stream>>>(tabQ, tabK);
    wt_kernel<<<dim3(768), dim3(256), 0, stream>>>(WQ, WK, WV, Wt);
    proj_kernel<<<dim3(256, 2), dim3(256), 0, stream>>>(X, Mem, Wt, tabQ, tabK, Qb, Kb, Vt);
    ret_kernel<<<dim3(256), dim3(256), 0, stream>>>(Qb, Kb, Vt, out);
}

// Round 7
// 144.366 us; speedup vs baseline: 1.3269x; 1.3269x over previous
//
#include <hip/hip_runtime.h>
#include <hip/hip_bf16.h>

#define S_LEN 4096
#define HID   512
#define HD    128
#define LOG2_GAMMA (-0.0458036933f)   // log2(0.96875)

typedef short bf16x8 __attribute__((ext_vector_type(8)));
typedef float f32x4  __attribute__((ext_vector_type(4)));
typedef unsigned short u16;

static __device__ __forceinline__ u16 f2bf(float f) {
    union { float f; unsigned u; } v; v.f = f;
    unsigned r = (v.u + 0x7fffu + ((v.u >> 16) & 1u)) >> 16;  // RNE
    return (u16)r;
}

static __device__ __forceinline__ unsigned pk2(float lo, float hi) {
    __hip_bfloat162 h = __float22bfloat162_rn(make_float2(lo, hi));
    union { __hip_bfloat162 h; unsigned u; } c; c.h = h; return c.u;
}
static __device__ __forceinline__ bf16x8 pack8(float4 a, float4 b) {
    union { unsigned u[4]; bf16x8 v; } r;
    r.u[0] = pk2(a.x, a.y); r.u[1] = pk2(a.z, a.w);
    r.u[2] = pk2(b.x, b.y); r.u[3] = pk2(b.z, b.w);
    return r.v;
}

// async global->LDS, 16B per lane; LDS dest = wave-uniform base + lane*16
static __device__ __forceinline__ void gload16(const void* g, void* l) {
    __builtin_amdgcn_global_load_lds(
        (const __attribute__((address_space(1))) unsigned*)g,
        (__attribute__((address_space(3))) unsigned*)l, 16, 0, 0);
}

// ---------------- prep: xpos tables (blocks 0..1023) + weight transpose (1024..1791)
__global__ __launch_bounds__(256) void prep_kernel(const float* __restrict__ WQ,
                                                   const float* __restrict__ WK,
                                                   const float* __restrict__ WV,
                                                   u16* __restrict__ Wt,
                                                   float2* __restrict__ tabQ,
                                                   float2* __restrict__ tabK) {
    if (blockIdx.x < 1024) {
        int idx = blockIdx.x * 256 + threadIdx.x;      // 4096*64 items
        int n = idx >> 6, i = idx & 63;
        float base  = (2.0f * i + 51.2f) * (1.0f / 179.2f);   // (2i+0.4d)/(1.4d), d=128
        float power = (float)n * (1.0f / 512.0f);
        float scale = exp2f(power * log2f(base));
        float inv_freq = exp2f(-(float)i * (13.287712379549449f / 64.0f)); // 10000^(-i/64)
        float theta = (float)n * inv_freq;
        float s, c;
        sincosf(theta, &s, &c);
        tabQ[idx] = make_float2(c * scale, s * scale);
        float is = 1.0f / scale;
        tabK[idx] = make_float2(c * is, s * is);
    } else {
        int idx = (blockIdx.x - 1024) * 256 + threadIdx.x;   // 3*128*512 items
        int w = idx >> 16;
        int rem = idx & 65535;
        int c = rem >> 9, k = rem & 511;
        const float* src = (w == 0) ? WQ : (w == 1) ? WK : WV;
        Wt[idx] = f2bf(src[k * HD + c]);
    }
}

// ---------------- proj v7: single launch, staged BK=32, fused Q | (K+V) ------------
// grid (256, 2); block 256 (4 waves). Tile 64 tokens x 128 cols, 16 chunks of BK=32.
// y=0: Q from X (B_lds[..][0] only). y=1: K and V from Mem, A staged ONCE.
// A swizzle: unit s of row r at slot r*8 + (s ^ (r&7)); B: unit s of col c at
// slot c*4 + (s ^ ((c>>1)&3)). Both read patterns bank-balanced for ds_read_b128.
__global__ __launch_bounds__(256) void proj_kernel(const float* __restrict__ X,
                                                   const float* __restrict__ Mem,
                                                   const u16* __restrict__ Wt,
                                                   const float2* __restrict__ tabQ,
                                                   const float2* __restrict__ tabK,
                                                   u16* __restrict__ Qo,
                                                   u16* __restrict__ Ko,
                                                   u16* __restrict__ Vt) {
    __shared__ __align__(16) float A_lds[2][2048];      // 2 x 8KB
    __shared__ __align__(16) u16   B_lds[2][2][4096];   // 2 bufs x 2 mats x 8KB
    const int tid  = threadIdx.x;
    const int wave = tid >> 6, lane = tid & 63;
    const int l15  = lane & 15, quad = lane >> 4;
    const int rt_base = blockIdx.x * 64;

    if (blockIdx.y == 0) {
        // ------------------------------ Q from X ------------------------------
        auto stage = [&](int ch, int p) {
            const int kc0 = ch * 32;
#pragma unroll
            for (int i = 0; i < 2; ++i) {
                int L = i * 256 + tid;
                int row = L >> 3;
                int s = (L & 7) ^ (row & 7);
                gload16(X + (size_t)(rt_base + row) * HID + kc0 + s * 4,
                        &A_lds[p][(i * 256 + wave * 64) * 4]);
            }
#pragma unroll
            for (int i = 0; i < 2; ++i) {
                int L = i * 256 + tid;
                int col = L >> 2;
                int s = (L & 3) ^ ((col >> 1) & 3);
                gload16(Wt + (size_t)col * HID + kc0 + s * 8,
                        &B_lds[p][0][(i * 256 + wave * 64) * 8]);
            }
        };

        f32x4 acc[8];
#pragma unroll
        for (int ct = 0; ct < 8; ++ct) acc[ct] = (f32x4){0.f, 0.f, 0.f, 0.f};

        stage(0, 0);
        for (int ch = 0; ch < 16; ++ch) {
            const int p = ch & 1;
            __syncthreads();
            if (ch < 15) stage(ch + 1, p ^ 1);
            const int arow = wave * 16 + l15;
            float4 af0 = *(const float4*)&A_lds[p][(arow * 8 + ((quad * 2    ) ^ (l15 & 7))) * 4];
            float4 af1 = *(const float4*)&A_lds[p][(arow * 8 + ((quad * 2 + 1) ^ (l15 & 7))) * 4];
            bf16x8 a = pack8(af0, af1);
#pragma unroll
            for (int ct = 0; ct < 8; ++ct) {
                const int bu = (ct * 16 + l15) * 4 + (quad ^ ((l15 >> 1) & 3));
                bf16x8 b0 = *(const bf16x8*)&B_lds[p][0][bu * 8];
                acc[ct] = __builtin_amdgcn_mfma_f32_16x16x32_bf16(a, b0, acc[ct], 0, 0, 0);
            }
        }

        // Q xpos epilogue (table)
#pragma unroll
        for (int ct = 0; ct < 8; ++ct) {
            int j = ct * 16 + l15;
            int i = j >> 1;
            float sgn = (j & 1) ? 1.0f : -1.0f;
#pragma unroll
            for (int r = 0; r < 4; ++r) {
                int t = rt_base + wave * 16 + quad * 4 + r;
                int n = t & 4095;
                float2 cs = tabQ[n * 64 + i];
                float v = acc[ct][r];
                float partner = __shfl_xor(v, 1, 64);
                Qo[(size_t)t * HD + j] = f2bf(v * cs.x + sgn * partner * cs.y);
            }
        }
    } else {
        // --------------------------- K and V from Mem -------------------------
        const u16* WK_ = Wt + 65536;
        const u16* WV_ = Wt + 131072;

        auto stage = [&](int ch, int p) {
            const int kc0 = ch * 32;
#pragma unroll
            for (int i = 0; i < 2; ++i) {
                int L = i * 256 + tid;
                int row = L >> 3;
                int s = (L & 7) ^ (row & 7);
                gload16(Mem + (size_t)(rt_base + row) * HID + kc0 + s * 4,
                        &A_lds[p][(i * 256 + wave * 64) * 4]);
            }
#pragma unroll
            for (int i = 0; i < 2; ++i) {
                int L = i * 256 + tid;
                int col = L >> 2;
                int s = (L & 3) ^ ((col >> 1) & 3);
                gload16(WK_ + (size_t)col * HID + kc0 + s * 8,
                        &B_lds[p][0][(i * 256 + wave * 64) * 8]);
            }
#pragma unroll
            for (int i = 0; i < 2; ++i) {
                int L = i * 256 + tid;
                int col = L >> 2;
                int s = (L & 3) ^ ((col >> 1) & 3);
                gload16(WV_ + (size_t)col * HID + kc0 + s * 8,
                        &B_lds[p][1][(i * 256 + wave * 64) * 8]);
            }
        };

        f32x4 acc0[8], acc1[8];
#pragma unroll
        for (int ct = 0; ct < 8; ++ct) {
            acc0[ct] = (f32x4){0.f, 0.f, 0.f, 0.f};
            acc1[ct] = (f32x4){0.f, 0.f, 0.f, 0.f};
        }

        stage(0, 0);
        for (int ch = 0; ch < 16; ++ch) {
            const int p = ch & 1;
            __syncthreads();
            if (ch < 15) stage(ch + 1, p ^ 1);
            const int arow = wave * 16 + l15;
            float4 af0 = *(const float4*)&A_lds[p][(arow * 8 + ((quad * 2    ) ^ (l15 & 7))) * 4];
            float4 af1 = *(const float4*)&A_lds[p][(arow * 8 + ((quad * 2 + 1) ^ (l15 & 7))) * 4];
            bf16x8 a = pack8(af0, af1);
#pragma unroll
            for (int ct = 0; ct < 8; ++ct) {
                const int bu = (ct * 16 + l15) * 4 + (quad ^ ((l15 >> 1) & 3));
                bf16x8 b0 = *(const bf16x8*)&B_lds[p][0][bu * 8];
                bf16x8 b1 = *(const bf16x8*)&B_lds[p][1][bu * 8];
                acc0[ct] = __builtin_amdgcn_mfma_f32_16x16x32_bf16(a, b0, acc0[ct], 0, 0, 0);
                acc1[ct] = __builtin_amdgcn_mfma_f32_16x16x32_bf16(a, b1, acc1[ct], 0, 0, 0);
            }
        }

        // K xpos epilogue (table)
#pragma unroll
        for (int ct = 0; ct < 8; ++ct) {
            int j = ct * 16 + l15;
            int i = j >> 1;
            float sgn = (j & 1) ? 1.0f : -1.0f;
#pragma unroll
            for (int r = 0; r < 4; ++r) {
                int t = rt_base + wave * 16 + quad * 4 + r;
                int n = t & 4095;
                float2 cs = tabK[n * 64 + i];
                float v = acc0[ct][r];
                float partner = __shfl_xor(v, 1, 64);
                Ko[(size_t)t * HD + j] = f2bf(v * cs.x + sgn * partner * cs.y);
            }
        }

        // V transpose via LDS scratch (reuses B_lds: 20KB <= 32KB) -> Vt[b][h][s]
        u16* Vs = (u16*)&B_lds[0][0][0];
        __syncthreads();                 // all waves done reading K-loop LDS
#pragma unroll
        for (int ct = 0; ct < 8; ++ct) {
            int col = ct * 16 + l15;
#pragma unroll
            for (int r = 0; r < 4; ++r)
                Vs[col * 80 + wave * 16 + quad * 4 + r] = f2bf(acc1[ct][r]);
        }
        __syncthreads();
        int b = rt_base >> 12, sb = rt_base & 4095;
        int h = tid >> 1, sof = (tid & 1) * 32;
#pragma unroll
        for (int pp = 0; pp < 4; ++pp) {
            bf16x8 v = *(const bf16x8*)&Vs[h * 80 + sof + pp * 8];
            *(bf16x8*)(Vt + (size_t)(b * 128 + h) * S_LEN + sb + sof + pp * 8) = v;
        }
    }
}

// ---------------- windowed retention v3 (R3-verbatim, known good) ------------------
__global__ __launch_bounds__(256) void ret_kernel(const u16* __restrict__ Qb,
                                                  const u16* __restrict__ Kb,
                                                  const u16* __restrict__ Vt,
                                                  float* __restrict__ out) {
    __shared__ __align__(16) u16   K_lds[2][8192];      // 2 x 16KB: 64 kv x 128 hd
    __shared__ __align__(16) float P_lds[4][16][68];    // per-wave 16x64 fp32 strip
    const int tid  = threadIdx.x;
    const int wave = tid >> 6, lane = tid & 63;
    const int l15  = lane & 15, quad = lane >> 4;
    const int b  = blockIdx.x >> 6;
    const int qt = (blockIdx.x & 63) * 64;
    const int qw = qt + wave * 16;

    auto stageK = [&](int kv0, int p) {
#pragma unroll
        for (int i = 0; i < 4; ++i) {
            int u = i * 256 + tid;
            int kvr = u >> 4;
            int s = (u & 15) ^ (kvr & 15);
            gload16(Kb + (size_t)(b * S_LEN + kv0 + kvr) * HD + s * 8,
                    &K_lds[p][(i * 256 + wave * 64) * 8]);
        }
    };

    const size_t tq = (size_t)(b * S_LEN + qw + l15);
    bf16x8 qfrag[4];
#pragma unroll
    for (int kc = 0; kc < 4; ++kc)
        qfrag[kc] = *(const bf16x8*)(Qb + tq * HD + kc * 32 + quad * 8);

    f32x4 acco[8];
#pragma unroll
    for (int ht = 0; ht < 8; ++ht) acco[ht] = (f32x4){0.f, 0.f, 0.f, 0.f};

    int kv_lo = qt - 448; if (kv_lo < 0) kv_lo = 0;   // γ^449 ≈ 6e-7: below threshold
    const int nt = (qt + 64 - kv_lo) >> 6;

    stageK(kv_lo, 0);
    for (int it = 0; it < nt; ++it) {
        const int p = it & 1;
        const int kv0 = kv_lo + it * 64;
        __syncthreads();
        if (it + 1 < nt) stageK(kv0 + 64, p ^ 1);

        bf16x8 vf[8][2];
#pragma unroll
        for (int ht = 0; ht < 8; ++ht) {
            const u16* vb = Vt + (size_t)(b * HD + ht * 16 + l15) * S_LEN + kv0 + quad * 8;
            vf[ht][0] = *(const bf16x8*)vb;
            vf[ht][1] = *(const bf16x8*)(vb + 32);
        }

        f32x4 accs[4];
#pragma unroll
        for (int ct = 0; ct < 4; ++ct) accs[ct] = (f32x4){0.f, 0.f, 0.f, 0.f};
#pragma unroll
        for (int ct = 0; ct < 4; ++ct) {
            const int kvr = ct * 16 + l15;
#pragma unroll
            for (int kc = 0; kc < 4; ++kc) {
                bf16x8 kf = *(const bf16x8*)
                    &K_lds[p][(kvr * 16 + ((kc * 4 + quad) ^ (kvr & 15))) * 8];
                accs[ct] = __builtin_amdgcn_mfma_f32_16x16x32_bf16(qfrag[kc], kf, accs[ct], 0, 0, 0);
            }
        }
#pragma unroll
        for (int ct = 0; ct < 4; ++ct) {
            int kvi = kv0 + ct * 16 + l15;
#pragma unroll
            for (int r = 0; r < 4; ++r) {
                int d = (qw + quad * 4 + r) - kvi;
                float w = exp2f((float)d * LOG2_GAMMA);
                P_lds[wave][quad * 4 + r][ct * 16 + l15] = (d >= 0) ? accs[ct][r] * w : 0.0f;
            }
        }
        float4 p00 = *(const float4*)&P_lds[wave][l15][quad * 8];
        float4 p01 = *(const float4*)&P_lds[wave][l15][quad * 8 + 4];
        float4 p10 = *(const float4*)&P_lds[wave][l15][32 + quad * 8];
        float4 p11 = *(const float4*)&P_lds[wave][l15][32 + quad * 8 + 4];
        bf16x8 pa0 = pack8(p00, p01);
        bf16x8 pa1 = pack8(p10, p11);
#pragma unroll
        for (int ht = 0; ht < 8; ++ht) {
            acco[ht] = __builtin_amdgcn_mfma_f32_16x16x32_bf16(pa0, vf[ht][0], acco[ht], 0, 0, 0);
            acco[ht] = __builtin_amdgcn_mfma_f32_16x16x32_bf16(pa1, vf[ht][1], acco[ht], 0, 0, 0);
        }
    }

#pragma unroll
    for (int ht = 0; ht < 8; ++ht)
#pragma unroll
        for (int r = 0; r < 4; ++r)
            out[(size_t)(b * S_LEN + qw + quad * 4 + r) * HD + ht * 16 + l15] = acco[ht][r];
}

extern "C" void kernel_launch(void* const* d_in, const int* in_sizes, int n_in,
                              void* d_out, int out_size, void* d_ws, size_t ws_size,
                              hipStream_t stream) {
    const float* X   = (const float*)d_in[0];
    const float* Mem = (const float*)d_in[1];
    const float* WQ  = (const float*)d_in[2];
    const float* WK  = (const float*)d_in[3];
    const float* WV  = (const float*)d_in[4];
    float* out = (float*)d_out;

    char* ws = (char*)d_ws;
    u16*    Qb   = (u16*)(ws);                         // 4 MB  bf16 [16384][128]
    u16*    Kb   = (u16*)(ws + ((size_t)4 << 20));     // 4 MB
    u16*    Vt   = (u16*)(ws + ((size_t)8 << 20));     // 4 MB  bf16 [4][128][4096]
    u16*    Wt   = (u16*)(ws + ((size_t)12 << 20));    // 384 KB bf16 [3][128][512]
    float2* tabQ = (float2*)(ws + ((size_t)13 << 20)); // 2 MB
    float2* tabK = (float2*)(ws + ((size_t)15 << 20)); // 2 MB

    prep_kernel<<<dim3(1792), dim3(256), 0, stream>>>(WQ, WK, WV, Wt, tabQ, tabK);
    proj_kernel<<<dim3(256, 2), dim3(256), 0, stream>>>(X, Mem, Wt, tabQ, tabK, Qb, Kb, Vt);
    ret_kernel<<<dim3(256), dim3(256), 0, stream>>>(Qb, Kb, Vt, out);
}

// Round 8
// 143.126 us; speedup vs baseline: 1.3384x; 1.0087x over previous
//
#include <hip/hip_runtime.h>
#include <hip/hip_bf16.h>

#define S_LEN 4096
#define HID   512
#define HD    128
#define LOG2_GAMMA (-0.0458036933f)   // log2(0.96875)

typedef short bf16x8 __attribute__((ext_vector_type(8)));
typedef float f32x4  __attribute__((ext_vector_type(4)));
typedef unsigned short u16;

static __device__ __forceinline__ u16 f2bf(float f) {
    union { float f; unsigned u; } v; v.f = f;
    unsigned r = (v.u + 0x7fffu + ((v.u >> 16) & 1u)) >> 16;  // RNE
    return (u16)r;
}

static __device__ __forceinline__ unsigned pk2(float lo, float hi) {
    __hip_bfloat162 h = __float22bfloat162_rn(make_float2(lo, hi));
    union { __hip_bfloat162 h; unsigned u; } c; c.h = h; return c.u;
}
static __device__ __forceinline__ bf16x8 pack8(float4 a, float4 b) {
    union { unsigned u[4]; bf16x8 v; } r;
    r.u[0] = pk2(a.x, a.y); r.u[1] = pk2(a.z, a.w);
    r.u[2] = pk2(b.x, b.y); r.u[3] = pk2(b.z, b.w);
    return r.v;
}

// async global->LDS, 16B per lane; LDS dest = wave-uniform base + lane*16
static __device__ __forceinline__ void gload16(const void* g, void* l) {
    __builtin_amdgcn_global_load_lds(
        (const __attribute__((address_space(1))) unsigned*)g,
        (__attribute__((address_space(3))) unsigned*)l, 16, 0, 0);
}

// ---------------- prep: xpos tables (blocks 0..1023) + weight transpose (1024..1791)
__global__ __launch_bounds__(256) void prep_kernel(const float* __restrict__ WQ,
                                                   const float* __restrict__ WK,
                                                   const float* __restrict__ WV,
                                                   u16* __restrict__ Wt,
                                                   float2* __restrict__ tabQ,
                                                   float2* __restrict__ tabK) {
    if (blockIdx.x < 1024) {
        int idx = blockIdx.x * 256 + threadIdx.x;      // 4096*64 items
        int n = idx >> 6, i = idx & 63;
        float base  = (2.0f * i + 51.2f) * (1.0f / 179.2f);   // (2i+0.4d)/(1.4d), d=128
        float power = (float)n * (1.0f / 512.0f);
        float scale = exp2f(power * log2f(base));
        float inv_freq = exp2f(-(float)i * (13.287712379549449f / 64.0f)); // 10000^(-i/64)
        float theta = (float)n * inv_freq;
        float s, c;
        sincosf(theta, &s, &c);
        tabQ[idx] = make_float2(c * scale, s * scale);
        float is = 1.0f / scale;
        tabK[idx] = make_float2(c * is, s * is);
    } else {
        int idx = (blockIdx.x - 1024) * 256 + threadIdx.x;   // 3*128*512 items
        int w = idx >> 16;
        int rem = idx & 65535;
        int c = rem >> 9, k = rem & 511;
        const float* src = (w == 0) ? WQ : (w == 1) ? WK : WV;
        Wt[idx] = f2bf(src[k * HD + c]);
    }
}

// ---------------- proj v7 (R7-verbatim): single launch, staged BK=32, fused Q|(K+V) -
__global__ __launch_bounds__(256) void proj_kernel(const float* __restrict__ X,
                                                   const float* __restrict__ Mem,
                                                   const u16* __restrict__ Wt,
                                                   const float2* __restrict__ tabQ,
                                                   const float2* __restrict__ tabK,
                                                   u16* __restrict__ Qo,
                                                   u16* __restrict__ Ko,
                                                   u16* __restrict__ Vt) {
    __shared__ __align__(16) float A_lds[2][2048];      // 2 x 8KB
    __shared__ __align__(16) u16   B_lds[2][2][4096];   // 2 bufs x 2 mats x 8KB
    const int tid  = threadIdx.x;
    const int wave = tid >> 6, lane = tid & 63;
    const int l15  = lane & 15, quad = lane >> 4;
    const int rt_base = blockIdx.x * 64;

    if (blockIdx.y == 0) {
        // ------------------------------ Q from X ------------------------------
        auto stage = [&](int ch, int p) {
            const int kc0 = ch * 32;
#pragma unroll
            for (int i = 0; i < 2; ++i) {
                int L = i * 256 + tid;
                int row = L >> 3;
                int s = (L & 7) ^ (row & 7);
                gload16(X + (size_t)(rt_base + row) * HID + kc0 + s * 4,
                        &A_lds[p][(i * 256 + wave * 64) * 4]);
            }
#pragma unroll
            for (int i = 0; i < 2; ++i) {
                int L = i * 256 + tid;
                int col = L >> 2;
                int s = (L & 3) ^ ((col >> 1) & 3);
                gload16(Wt + (size_t)col * HID + kc0 + s * 8,
                        &B_lds[p][0][(i * 256 + wave * 64) * 8]);
            }
        };

        f32x4 acc[8];
#pragma unroll
        for (int ct = 0; ct < 8; ++ct) acc[ct] = (f32x4){0.f, 0.f, 0.f, 0.f};

        stage(0, 0);
        for (int ch = 0; ch < 16; ++ch) {
            const int p = ch & 1;
            __syncthreads();
            if (ch < 15) stage(ch + 1, p ^ 1);
            const int arow = wave * 16 + l15;
            float4 af0 = *(const float4*)&A_lds[p][(arow * 8 + ((quad * 2    ) ^ (l15 & 7))) * 4];
            float4 af1 = *(const float4*)&A_lds[p][(arow * 8 + ((quad * 2 + 1) ^ (l15 & 7))) * 4];
            bf16x8 a = pack8(af0, af1);
#pragma unroll
            for (int ct = 0; ct < 8; ++ct) {
                const int bu = (ct * 16 + l15) * 4 + (quad ^ ((l15 >> 1) & 3));
                bf16x8 b0 = *(const bf16x8*)&B_lds[p][0][bu * 8];
                acc[ct] = __builtin_amdgcn_mfma_f32_16x16x32_bf16(a, b0, acc[ct], 0, 0, 0);
            }
        }

        // Q xpos epilogue (table)
#pragma unroll
        for (int ct = 0; ct < 8; ++ct) {
            int j = ct * 16 + l15;
            int i = j >> 1;
            float sgn = (j & 1) ? 1.0f : -1.0f;
#pragma unroll
            for (int r = 0; r < 4; ++r) {
                int t = rt_base + wave * 16 + quad * 4 + r;
                int n = t & 4095;
                float2 cs = tabQ[n * 64 + i];
                float v = acc[ct][r];
                float partner = __shfl_xor(v, 1, 64);
                Qo[(size_t)t * HD + j] = f2bf(v * cs.x + sgn * partner * cs.y);
            }
        }
    } else {
        // --------------------------- K and V from Mem -------------------------
        const u16* WK_ = Wt + 65536;
        const u16* WV_ = Wt + 131072;

        auto stage = [&](int ch, int p) {
            const int kc0 = ch * 32;
#pragma unroll
            for (int i = 0; i < 2; ++i) {
                int L = i * 256 + tid;
                int row = L >> 3;
                int s = (L & 7) ^ (row & 7);
                gload16(Mem + (size_t)(rt_base + row) * HID + kc0 + s * 4,
                        &A_lds[p][(i * 256 + wave * 64) * 4]);
            }
#pragma unroll
            for (int i = 0; i < 2; ++i) {
                int L = i * 256 + tid;
                int col = L >> 2;
                int s = (L & 3) ^ ((col >> 1) & 3);
                gload16(WK_ + (size_t)col * HID + kc0 + s * 8,
                        &B_lds[p][0][(i * 256 + wave * 64) * 8]);
            }
#pragma unroll
            for (int i = 0; i < 2; ++i) {
                int L = i * 256 + tid;
                int col = L >> 2;
                int s = (L & 3) ^ ((col >> 1) & 3);
                gload16(WV_ + (size_t)col * HID + kc0 + s * 8,
                        &B_lds[p][1][(i * 256 + wave * 64) * 8]);
            }
        };

        f32x4 acc0[8], acc1[8];
#pragma unroll
        for (int ct = 0; ct < 8; ++ct) {
            acc0[ct] = (f32x4){0.f, 0.f, 0.f, 0.f};
            acc1[ct] = (f32x4){0.f, 0.f, 0.f, 0.f};
        }

        stage(0, 0);
        for (int ch = 0; ch < 16; ++ch) {
            const int p = ch & 1;
            __syncthreads();
            if (ch < 15) stage(ch + 1, p ^ 1);
            const int arow = wave * 16 + l15;
            float4 af0 = *(const float4*)&A_lds[p][(arow * 8 + ((quad * 2    ) ^ (l15 & 7))) * 4];
            float4 af1 = *(const float4*)&A_lds[p][(arow * 8 + ((quad * 2 + 1) ^ (l15 & 7))) * 4];
            bf16x8 a = pack8(af0, af1);
#pragma unroll
            for (int ct = 0; ct < 8; ++ct) {
                const int bu = (ct * 16 + l15) * 4 + (quad ^ ((l15 >> 1) & 3));
                bf16x8 b0 = *(const bf16x8*)&B_lds[p][0][bu * 8];
                bf16x8 b1 = *(const bf16x8*)&B_lds[p][1][bu * 8];
                acc0[ct] = __builtin_amdgcn_mfma_f32_16x16x32_bf16(a, b0, acc0[ct], 0, 0, 0);
                acc1[ct] = __builtin_amdgcn_mfma_f32_16x16x32_bf16(a, b1, acc1[ct], 0, 0, 0);
            }
        }

        // K xpos epilogue (table)
#pragma unroll
        for (int ct = 0; ct < 8; ++ct) {
            int j = ct * 16 + l15;
            int i = j >> 1;
            float sgn = (j & 1) ? 1.0f : -1.0f;
#pragma unroll
            for (int r = 0; r < 4; ++r) {
                int t = rt_base + wave * 16 + quad * 4 + r;
                int n = t & 4095;
                float2 cs = tabK[n * 64 + i];
                float v = acc0[ct][r];
                float partner = __shfl_xor(v, 1, 64);
                Ko[(size_t)t * HD + j] = f2bf(v * cs.x + sgn * partner * cs.y);
            }
        }

        // V transpose via LDS scratch (reuses B_lds: 20KB <= 32KB) -> Vt[b][h][s]
        u16* Vs = (u16*)&B_lds[0][0][0];
        __syncthreads();                 // all waves done reading K-loop LDS
#pragma unroll
        for (int ct = 0; ct < 8; ++ct) {
            int col = ct * 16 + l15;
#pragma unroll
            for (int r = 0; r < 4; ++r)
                Vs[col * 80 + wave * 16 + quad * 4 + r] = f2bf(acc1[ct][r]);
        }
        __syncthreads();
        int b = rt_base >> 12, sb = rt_base & 4095;
        int h = tid >> 1, sof = (tid & 1) * 32;
#pragma unroll
        for (int pp = 0; pp < 4; ++pp) {
            bf16x8 v = *(const bf16x8*)&Vs[h * 80 + sof + pp * 8];
            *(bf16x8*)(Vt + (size_t)(b * 128 + h) * S_LEN + sb + sof + pp * 8) = v;
        }
    }
}

// ---------------- windowed retention v5: 32-row q-tiles, 512 blocks, dup-QK --------
// grid 512 (b*128 + qtile32); block 256 (4 waves). wave: rt = w&1 (16 q-rows),
// hh = w>>1 (head-half for PV). QK duplicated across the two hh waves so the P
// strip stays wave-private -> still ONE barrier per tile. Tiles: <=8 (vs 9).
__global__ __launch_bounds__(256) void ret_kernel(const u16* __restrict__ Qb,
                                                  const u16* __restrict__ Kb,
                                                  const u16* __restrict__ Vt,
                                                  float* __restrict__ out) {
    __shared__ __align__(16) u16   K_lds[2][8192];      // 2 x 16KB: 64 kv x 128 hd
    __shared__ __align__(16) float P_lds[4][16][68];    // per-wave 16x64 fp32 strip
    const int tid  = threadIdx.x;
    const int wave = tid >> 6, lane = tid & 63;
    const int l15  = lane & 15, quad = lane >> 4;
    const int b  = blockIdx.x >> 7;
    const int qt = (blockIdx.x & 127) * 32;
    const int rt = wave & 1;          // q row-tile (16 rows)
    const int hh = wave >> 1;         // head-half (heads hh*4 .. hh*4+3)
    const int qw = qt + rt * 16;

    auto stageK = [&](int kv0, int p) {
#pragma unroll
        for (int i = 0; i < 4; ++i) {
            int u = i * 256 + tid;
            int kvr = u >> 4;
            int s = (u & 15) ^ (kvr & 15);
            gload16(Kb + (size_t)(b * S_LEN + kv0 + kvr) * HD + s * 8,
                    &K_lds[p][(i * 256 + wave * 64) * 8]);
        }
    };

    const size_t tq = (size_t)(b * S_LEN + qw + l15);
    bf16x8 qfrag[4];
#pragma unroll
    for (int kc = 0; kc < 4; ++kc)
        qfrag[kc] = *(const bf16x8*)(Qb + tq * HD + kc * 32 + quad * 8);

    f32x4 acco[4];
#pragma unroll
    for (int hc = 0; hc < 4; ++hc) acco[hc] = (f32x4){0.f, 0.f, 0.f, 0.f};

    int kv_lo = qt - 448;             // covers all decay d<=448 (γ^449≈6e-7)
    kv_lo &= ~63;                     // 64-align (only extends the window)
    if (kv_lo < 0) kv_lo = 0;
    const int nt = (qt + 32 - kv_lo + 63) >> 6;   // <= 8 tiles

    stageK(kv_lo, 0);
    for (int it = 0; it < nt; ++it) {
        const int p = it & 1;
        const int kv0 = kv_lo + it * 64;
        __syncthreads();               // K buf p ready; p^1 free
        if (it + 1 < nt) stageK(kv0 + 64, p ^ 1);

        // V prefetch for this wave's 4 head-tiles (consumed at tile end)
        bf16x8 vf[4][2];
#pragma unroll
        for (int hc = 0; hc < 4; ++hc) {
            const u16* vb = Vt + (size_t)(b * HD + (hh * 4 + hc) * 16 + l15) * S_LEN
                            + kv0 + quad * 8;
            vf[hc][0] = *(const bf16x8*)vb;
            vf[hc][1] = *(const bf16x8*)(vb + 32);
        }

        // ---- S = Q K^T (16x64, duplicated across hh pair) ----
        f32x4 accs[4];
#pragma unroll
        for (int ct = 0; ct < 4; ++ct) accs[ct] = (f32x4){0.f, 0.f, 0.f, 0.f};
#pragma unroll
        for (int ct = 0; ct < 4; ++ct) {
            const int kvr = ct * 16 + l15;
#pragma unroll
            for (int kc = 0; kc < 4; ++kc) {
                bf16x8 kf = *(const bf16x8*)
                    &K_lds[p][(kvr * 16 + ((kc * 4 + quad) ^ (kvr & 15))) * 8];
                accs[ct] = __builtin_amdgcn_mfma_f32_16x16x32_bf16(qfrag[kc], kf, accs[ct], 0, 0, 0);
            }
        }
        // ---- decay + causal mask -> wave-private P strip (no barrier) ----
#pragma unroll
        for (int ct = 0; ct < 4; ++ct) {
            int kvi = kv0 + ct * 16 + l15;
#pragma unroll
            for (int r = 0; r < 4; ++r) {
                int d = (qw + quad * 4 + r) - kvi;
                float w = exp2f((float)d * LOG2_GAMMA);
                P_lds[wave][quad * 4 + r][ct * 16 + l15] = (d >= 0) ? accs[ct][r] * w : 0.0f;
            }
        }
        // ---- P as A-fragments (within-wave lgkmcnt only) ----
        float4 p00 = *(const float4*)&P_lds[wave][l15][quad * 8];
        float4 p01 = *(const float4*)&P_lds[wave][l15][quad * 8 + 4];
        float4 p10 = *(const float4*)&P_lds[wave][l15][32 + quad * 8];
        float4 p11 = *(const float4*)&P_lds[wave][l15][32 + quad * 8 + 4];
        bf16x8 pa0 = pack8(p00, p01);
        bf16x8 pa1 = pack8(p10, p11);
        // ---- O += P V for this wave's head-half ----
#pragma unroll
        for (int hc = 0; hc < 4; ++hc) {
            acco[hc] = __builtin_amdgcn_mfma_f32_16x16x32_bf16(pa0, vf[hc][0], acco[hc], 0, 0, 0);
            acco[hc] = __builtin_amdgcn_mfma_f32_16x16x32_bf16(pa1, vf[hc][1], acco[hc], 0, 0, 0);
        }
    }

    // ---- store O (fp32): rows qw.., cols hh*64 + hc*16 + l15 ----
#pragma unroll
    for (int hc = 0; hc < 4; ++hc)
#pragma unroll
        for (int r = 0; r < 4; ++r)
            out[(size_t)(b * S_LEN + qw + quad * 4 + r) * HD + hh * 64 + hc * 16 + l15]
                = acco[hc][r];
}

extern "C" void kernel_launch(void* const* d_in, const int* in_sizes, int n_in,
                              void* d_out, int out_size, void* d_ws, size_t ws_size,
                              hipStream_t stream) {
    const float* X   = (const float*)d_in[0];
    const float* Mem = (const float*)d_in[1];
    const float* WQ  = (const float*)d_in[2];
    const float* WK  = (const float*)d_in[3];
    const float* WV  = (const float*)d_in[4];
    float* out = (float*)d_out;

    char* ws = (char*)d_ws;
    u16*    Qb   = (u16*)(ws);                         // 4 MB  bf16 [16384][128]
    u16*    Kb   = (u16*)(ws + ((size_t)4 << 20));     // 4 MB
    u16*    Vt   = (u16*)(ws + ((size_t)8 << 20));     // 4 MB  bf16 [4][128][4096]
    u16*    Wt   = (u16*)(ws + ((size_t)12 << 20));    // 384 KB bf16 [3][128][512]
    float2* tabQ = (float2*)(ws + ((size_t)13 << 20)); // 2 MB
    float2* tabK = (float2*)(ws + ((size_t)15 << 20)); // 2 MB

    prep_kernel<<<dim3(1792), dim3(256), 0, stream>>>(WQ, WK, WV, Wt, tabQ, tabK);
    proj_kernel<<<dim3(256, 2), dim3(256), 0, stream>>>(X, Mem, Wt, tabQ, tabK, Qb, Kb, Vt);
    ret_kernel<<<dim3(512), dim3(256), 0, stream>>>(Qb, Kb, Vt, out);
}